// Round 12
// baseline (345.939 us; speedup 1.0000x reference)
//
#include <hip/hip_runtime.h>
#include <hip/hip_bf16.h>

// Attention head: context/softmax over (B=32, S=2048, DEC=512, ENC2=1024)
// d_in[0] = s (1,32,512) f32 | d_in[1] = enc (32,2048,1024) f32
// d_in[2] = W_attn (512,1536) f32 | d_in[3] = W_v (1,512) f32
// d_out = context (32,1024) f32 ++ soft (32,2048) f32

typedef __attribute__((ext_vector_type(8))) short bf16x8;
typedef __attribute__((ext_vector_type(4))) float f32x4;

#define PRIO1 __builtin_amdgcn_s_setprio(1)
#define PRIO0 __builtin_amdgcn_s_setprio(0)

static __device__ __forceinline__ unsigned short f2bf(float f) {
    union { float f; unsigned u; } v; v.f = f;
    unsigned r = (v.u + 0x7fffu + ((v.u >> 16) & 1u)) >> 16;  // RNE
    return (unsigned short)r;
}

static __device__ __forceinline__ unsigned pk2(float x, float y) {
    union { __hip_bfloat162 h; unsigned u; } c;
    c.h = __float22bfloat162_rn(make_float2(x, y));  // v_cvt_pk_bf16_f32
    return c.u;
}

static __device__ __forceinline__ float fast_tanh(float x) {
    return 1.0f - 2.0f / (__expf(2.0f * x) + 1.0f);
}

// ---------------- prep: sW[b,h] = sum_d s[b,d] * W_attn[h, d] ----------------
__global__ __launch_bounds__(256) void prep_sw(const float* __restrict__ s,
                                               const float* __restrict__ Wat,
                                               float* __restrict__ sW) {
    int id = blockIdx.x * 256 + threadIdx.x;   // 16384 = 32b * 512h
    int b = id >> 9, h = id & 511;
    const float4* wr = (const float4*)(Wat + (size_t)h * 1536);
    const float4* sr = (const float4*)(s + (size_t)b * 512);
    float acc = 0.f;
#pragma unroll 8
    for (int i = 0; i < 128; ++i) {
        float4 w = wr[i], sv = sr[i];
        acc += w.x * sv.x + w.y * sv.y + w.z * sv.z + w.w * sv.w;
    }
    sW[id] = acc;
}

// ------- prep: WebfB fragment-major bf16 repack of W_e = W_attn[:,512:] -----
// Layout: [ct(8)][h(32)][nf(4)][lane(64)][j(8)]  -> 65536 elems per ct
// element = W_e[col = ct*64+nf*16+(lane&15)][k = h*32+(lane>>4)*8+j]
__global__ __launch_bounds__(256) void prep_weB(const float* __restrict__ Wat,
                                                unsigned short* __restrict__ WebfB) {
    int tid = blockIdx.x * 256 + threadIdx.x;  // 0..65535
    int lane = tid & 63;
    int g = tid >> 6;                          // 0..1023
    int nf = g & 3, h = (g >> 2) & 31, ct = g >> 7;
    int col = ct * 64 + nf * 16 + (lane & 15);
    int k0 = h * 32 + (lane >> 4) * 8;
    const float* src = Wat + (size_t)col * 1536 + 512 + k0;
    float4 w0 = *(const float4*)src;
    float4 w1 = *(const float4*)(src + 4);
    union { unsigned short us[8]; int4 v; } p;
    p.us[0] = f2bf(w0.x); p.us[1] = f2bf(w0.y); p.us[2] = f2bf(w0.z); p.us[3] = f2bf(w0.w);
    p.us[4] = f2bf(w1.x); p.us[5] = f2bf(w1.y); p.us[6] = f2bf(w1.z); p.us[7] = f2bf(w1.w);
    *(int4*)(WebfB + (size_t)tid * 8) = p.v;
}

// ---------------- energy: attpart[ct][m] = sum_{64 cols of ct} tanh(..)*Wv ---
// ONE WAVE per block (64 thr), wave = 64 rows x 64 cols, grid 8192.
// NO LDS, NO BARRIERS: A-fragments are k-contiguous in enc -> loaded DIRECT
// from global (2 x dwordx4/lane), cvt'd in-register. B fragment-major from L2.
// 32 halves of 32-k; ping-pong reg zones, 2-half prefetch depth; compiler's
// exact per-register vmcnt waits are the only sync. setprio around MFMA.
// bid map: the 8 ct-sharers of an A-tile have the same bid%8 within one
// 64-bid window -> same XCD, concurrent -> A read once into that L2.
__global__ __launch_bounds__(64, 2) void energy_kernel(
    const float* __restrict__ enc, const unsigned short* __restrict__ WebfB,
    const float* __restrict__ sW, const float* __restrict__ Wv,
    float* __restrict__ attpart) {
    const int lane = threadIdx.x;      // 0..63
    const int bid = blockIdx.x;        // 0..8191
    const int ct = (bid >> 3) & 7;                   // col tile 0..7
    const int rt = (bid & 7) | ((bid >> 6) << 3);    // row tile 0..1023
    const int m0 = rt * 64;
    const int b = m0 >> 11;
    const int l15 = lane & 15;
    const int lkg = lane >> 4;         // k-group 0..3

    // A fragment bases: frag mf covers row m0+mf*16+l15, k = h*32 + lkg*8 + j
    const float* abase[4];
#pragma unroll
    for (int mf = 0; mf < 4; ++mf)
        abase[mf] = enc + (size_t)(m0 + mf * 16 + l15) * 1024 + lkg * 8;

    const unsigned short* bb = WebfB + (size_t)ct * 65536 + lane * 8;  // FIXED stride

    f32x4 acc[4][4];
#pragma unroll
    for (int mf = 0; mf < 4; ++mf)
#pragma unroll
        for (int nf = 0; nf < 4; ++nf) acc[mf][nf] = (f32x4){0.f, 0.f, 0.f, 0.f};

    float4 a0[8], a1[8];               // f32 A zones (4 frags x 2 float4)
    bf16x8 b0[4], b1[4];               // B zones

    auto LA = [&](float4 (&AZ)[8], int h) {
#pragma unroll
        for (int mf = 0; mf < 4; ++mf) {
            AZ[mf * 2 + 0] = *(const float4*)(abase[mf] + h * 32);
            AZ[mf * 2 + 1] = *(const float4*)(abase[mf] + h * 32 + 4);
        }
    };
    auto LB = [&](bf16x8 (&BZ)[4], int h) {
#pragma unroll
        for (int nf = 0; nf < 4; ++nf)
            BZ[nf] = *(const bf16x8*)(bb + (size_t)(h * 4 + nf) * 512);
    };
    auto HALF = [&](float4 (&AZ)[8], bf16x8 (&BZ)[4], int h) {
        bf16x8 abf[4];
#pragma unroll
        for (int mf = 0; mf < 4; ++mf) {
            union { unsigned u[4]; bf16x8 v; } c;
            c.u[0] = pk2(AZ[mf * 2].x, AZ[mf * 2].y);
            c.u[1] = pk2(AZ[mf * 2].z, AZ[mf * 2].w);
            c.u[2] = pk2(AZ[mf * 2 + 1].x, AZ[mf * 2 + 1].y);
            c.u[3] = pk2(AZ[mf * 2 + 1].z, AZ[mf * 2 + 1].w);
            abf[mf] = c.v;
        }
        if (h + 2 < 32) LA(AZ, h + 2);     // reuse freed zone, 2-half cover
        PRIO1;
#pragma unroll
        for (int nf = 0; nf < 4; ++nf)
#pragma unroll
            for (int mf = 0; mf < 4; ++mf)
                acc[mf][nf] = __builtin_amdgcn_mfma_f32_16x16x32_bf16(
                    abf[mf], BZ[nf], acc[mf][nf], 0, 0, 0);
        PRIO0;
        if (h + 2 < 32) LB(BZ, h + 2);
    };

    // prologue: 2 halves in flight
    LA(a0, 0); LB(b0, 0);
    LA(a1, 1); LB(b1, 1);

#pragma unroll
    for (int h = 0; h < 32; ++h) {
        if ((h & 1) == 0) HALF(a0, b0, h);
        else              HALF(a1, b1, h);
    }

    // epilogue: tanh + dot Wv over this wave's 64 cols (within-wave only)
    float sWv[4], wvv[4];
#pragma unroll
    for (int nf = 0; nf < 4; ++nf) {
        int col = ct * 64 + nf * 16 + l15;
        sWv[nf] = sW[(b << 9) + col];
        wvv[nf] = Wv[col];
    }
    float pa[4][4];
#pragma unroll
    for (int mf = 0; mf < 4; ++mf) {
#pragma unroll
        for (int r = 0; r < 4; ++r) pa[mf][r] = 0.f;
#pragma unroll
        for (int nf = 0; nf < 4; ++nf)
#pragma unroll
            for (int r = 0; r < 4; ++r)
                pa[mf][r] += fast_tanh(acc[mf][nf][r] + sWv[nf]) * wvv[nf];
    }
#pragma unroll
    for (int m = 1; m < 16; m <<= 1)
#pragma unroll
        for (int mf = 0; mf < 4; ++mf)
#pragma unroll
            for (int r = 0; r < 4; ++r)
                pa[mf][r] += __shfl_xor(pa[mf][r], m, 64);

    if (l15 == 0) {
#pragma unroll
        for (int mf = 0; mf < 4; ++mf) {
            float4 v = make_float4(pa[mf][0], pa[mf][1], pa[mf][2], pa[mf][3]);
            *(float4*)&attpart[(size_t)ct * 65536 + m0 + mf * 16 + lkg * 4] = v;
        }
    }
}

// ---------------- softmax over S=2048 per batch row (sums 8 col partials) ---
__global__ __launch_bounds__(256) void softmax_kernel(const float* __restrict__ attpart,
                                                      float* __restrict__ out) {
    int b = blockIdx.x, t = threadIdx.x;
    float v[8];
#pragma unroll
    for (int i = 0; i < 8; ++i) {
        int idx = b * 2048 + t + 256 * i;
        float s0 = 0.f;
#pragma unroll
        for (int c = 0; c < 8; ++c) s0 += attpart[c * 65536 + idx];
        v[i] = s0;
    }
    float mx = v[0];
#pragma unroll
    for (int i = 1; i < 8; ++i) mx = fmaxf(mx, v[i]);
#pragma unroll
    for (int m = 1; m < 64; m <<= 1) mx = fmaxf(mx, __shfl_xor(mx, m, 64));
    __shared__ float redm[4], reds[4];
    if ((t & 63) == 0) redm[t >> 6] = mx;
    __syncthreads();
    mx = fmaxf(fmaxf(redm[0], redm[1]), fmaxf(redm[2], redm[3]));
    float sum = 0.f;
#pragma unroll
    for (int i = 0; i < 8; ++i) { v[i] = __expf(v[i] - mx); sum += v[i]; }
#pragma unroll
    for (int m = 1; m < 64; m <<= 1) sum += __shfl_xor(sum, m, 64);
    if ((t & 63) == 0) reds[t >> 6] = sum;
    __syncthreads();
    sum = reds[0] + reds[1] + reds[2] + reds[3];
    float inv = 1.0f / sum;
    float* soft = out + 32768;
#pragma unroll
    for (int i = 0; i < 8; ++i) soft[b * 2048 + t + 256 * i] = v[i] * inv;
}

// ---------------- context partial: 16 chunks of 128 rows per batch ----------
__global__ __launch_bounds__(256) void ctx_partial(const float* __restrict__ enc,
                                                   const float* __restrict__ soft,
                                                   float* __restrict__ part) {
    int blk = blockIdx.x;               // b*16 + chunk
    int b = blk >> 4, s0 = (blk & 15) * 128;
    int t = threadIdx.x;
    float4 a = {0.f, 0.f, 0.f, 0.f};
    const float* base = enc + ((size_t)(b * 2048 + s0)) * 1024 + t * 4;
    const float* sw = soft + b * 2048 + s0;
#pragma unroll 4
    for (int s = 0; s < 128; ++s) {
        float w = sw[s];
        float4 e = *(const float4*)(base + (size_t)s * 1024);
        a.x += w * e.x; a.y += w * e.y; a.z += w * e.z; a.w += w * e.w;
    }
    *(float4*)(part + (size_t)blk * 1024 + t * 4) = a;
}

__global__ __launch_bounds__(256) void ctx_reduce(const float* __restrict__ part,
                                                  float* __restrict__ ctx) {
    int id = blockIdx.x * 256 + threadIdx.x;  // 32768 = 32b * 1024e
    int b = id >> 10, e = id & 1023;
    float s = 0.f;
#pragma unroll 8
    for (int c = 0; c < 16; ++c) s += part[((size_t)(b * 16 + c)) * 1024 + e];
    ctx[id] = s;
}

extern "C" void kernel_launch(void* const* d_in, const int* in_sizes, int n_in,
                              void* d_out, int out_size, void* d_ws, size_t ws_size,
                              hipStream_t stream) {
    const float* s   = (const float*)d_in[0];
    const float* enc = (const float*)d_in[1];
    const float* Wat = (const float*)d_in[2];
    const float* Wv  = (const float*)d_in[3];
    float* out = (float*)d_out;

    char* ws = (char*)d_ws;
    float* sW             = (float*)ws;                                   // 64 KiB
    unsigned short* WebfB = (unsigned short*)(ws + (64 << 10));           // 1 MiB
    float* attpart        = (float*)(ws + (64 << 10) + (1 << 20));        // 2 MiB
    float* part           = (float*)(ws + (64 << 10) + (3 << 20));        // 2 MiB

    prep_sw<<<64, 256, 0, stream>>>(s, Wat, sW);
    prep_weB<<<256, 256, 0, stream>>>(Wat, WebfB);
    energy_kernel<<<8192, 64, 0, stream>>>(enc, WebfB, sW, Wv, attpart);
    softmax_kernel<<<32, 256, 0, stream>>>(attpart, out);
    ctx_partial<<<512, 256, 0, stream>>>(enc, out + 32768, part);
    ctx_reduce<<<128, 256, 0, stream>>>(part, out);
}

// Round 13
// 207.211 us; speedup vs baseline: 1.6695x; 1.6695x over previous
//
#include <hip/hip_runtime.h>
#include <hip/hip_bf16.h>

// Attention head: context/softmax over (B=32, S=2048, DEC=512, ENC2=1024)
// d_in[0] = s (1,32,512) f32 | d_in[1] = enc (32,2048,1024) f32
// d_in[2] = W_attn (512,1536) f32 | d_in[3] = W_v (1,512) f32
// d_out = context (32,1024) f32 ++ soft (32,2048) f32

typedef __attribute__((ext_vector_type(8))) short bf16x8;
typedef __attribute__((ext_vector_type(4))) float f32x4;
typedef __attribute__((address_space(3))) unsigned lds_u32;
typedef const __attribute__((address_space(1))) unsigned g_u32;

#define SB0() __builtin_amdgcn_sched_barrier(0)
#define PRIO1 __builtin_amdgcn_s_setprio(1)
#define PRIO0 __builtin_amdgcn_s_setprio(0)

static __device__ __forceinline__ unsigned short f2bf(float f) {
    union { float f; unsigned u; } v; v.f = f;
    unsigned r = (v.u + 0x7fffu + ((v.u >> 16) & 1u)) >> 16;  // RNE
    return (unsigned short)r;
}

static __device__ __forceinline__ unsigned pk2(float x, float y) {
    union { __hip_bfloat162 h; unsigned u; } c;
    c.h = __float22bfloat162_rn(make_float2(x, y));  // v_cvt_pk_bf16_f32
    return c.u;
}

static __device__ __forceinline__ float fast_tanh(float x) {
    return 1.0f - 2.0f / (__expf(2.0f * x) + 1.0f);
}

// ---------------- prep: sW[b,h] = sum_d s[b,d] * W_attn[h, d] ----------------
__global__ __launch_bounds__(256) void prep_sw(const float* __restrict__ s,
                                               const float* __restrict__ Wat,
                                               float* __restrict__ sW) {
    int id = blockIdx.x * 256 + threadIdx.x;   // 16384 = 32b * 512h
    int b = id >> 9, h = id & 511;
    const float4* wr = (const float4*)(Wat + (size_t)h * 1536);
    const float4* sr = (const float4*)(s + (size_t)b * 512);
    float acc = 0.f;
#pragma unroll 8
    for (int i = 0; i < 128; ++i) {
        float4 w = wr[i], sv = sr[i];
        acc += w.x * sv.x + w.y * sv.y + w.z * sv.z + w.w * sv.w;
    }
    sW[id] = acc;
}

// ------- prep: WebfB fragment-major bf16 repack of W_e = W_attn[:,512:] -----
// g = ct*512 + step*32 + kk*16 + wc*4 + nf   (g = tid>>6, g < 1024)
// element = W_e[col = ct*256+wc*64+nf*16+(lane&15)][k = step*64+kk*32+(lane>>4)*8+j]
__global__ __launch_bounds__(256) void prep_weB(const float* __restrict__ Wat,
                                                unsigned short* __restrict__ WebfB) {
    int tid = blockIdx.x * 256 + threadIdx.x;  // 0..65535 (grid 256!)
    int lane = tid & 63;
    int g = tid >> 6;
    int nf = g & 3, wc = (g >> 2) & 3, kk = (g >> 4) & 1, step = (g >> 5) & 15, ct = (g >> 9) & 1;
    int col = ct * 256 + wc * 64 + nf * 16 + (lane & 15);
    int k0 = step * 64 + kk * 32 + (lane >> 4) * 8;
    const float* src = Wat + (size_t)col * 1536 + 512 + k0;
    float4 w0 = *(const float4*)src;
    float4 w1 = *(const float4*)(src + 4);
    union { unsigned short us[8]; int4 v; } p;
    p.us[0] = f2bf(w0.x); p.us[1] = f2bf(w0.y); p.us[2] = f2bf(w0.z); p.us[3] = f2bf(w0.w);
    p.us[4] = f2bf(w1.x); p.us[5] = f2bf(w1.y); p.us[6] = f2bf(w1.z); p.us[7] = f2bf(w1.w);
    *(int4*)(WebfB + (size_t)tid * 8) = p.v;
}

// ---------------- energy: m201-style 8-wave 4-phase deep pipeline ------------
// Block 256r x 256c, 512 thr, 8 waves (wr=wave>>2, wc=wave&3), wave 128x64.
// BK=64, 16 K-tiles. A: f32 in LDS via global_load_lds, 16B-chunk XOR swizzle
// (c16' = c16 ^ (row&7)), double-buffered (2x64 KB). Per tile: 4 phases of
// {8 ds_read_b128 -> 2 stage-issues -> barrier -> cvt+16 MFMA (setprio) ->
// barrier}; B(i+1)->regs in phase 3 after stages; vmcnt(8) counted wait.
__global__ __launch_bounds__(512, 2) void energy_kernel(
    const float* __restrict__ enc, const unsigned short* __restrict__ WebfB,
    const float* __restrict__ sW, const float* __restrict__ Wv,
    float* __restrict__ attpart) {
    __shared__ __align__(16) float buf0[16384];   // 64 KiB: [256 rows][64 f32]
    __shared__ __align__(16) float buf1[16384];
    __shared__ float lred[8][128];

    const int t = threadIdx.x;        // 0..511
    const int lane = t & 63;
    const int wave = t >> 6;          // 0..7
    const int wr = wave >> 2;         // M half 0..1
    const int wc = wave & 3;          // N quarter 0..3
    const int bid = blockIdx.x;       // 0..511
    const int ct = (bid >> 3) & 1;
    const int rt = (bid & 7) | ((bid >> 4) << 3);   // 0..255
    const int m0 = rt * 256;
    const int b = m0 >> 11;
    const int l15 = lane & 15;
    const int lkg = lane >> 4;

    // ---- staging addresses: issue (H,Q): thread covers LDS row q*32+wave*4+lkg
    // of half H, 16B chunk c16 = lane&15; global source chunk = c16 ^ (row&7).
    const int srow = wave * 4 + lkg;          // 0..31
    const int r7s = srow & 7;
    const float* gb0 = enc + (size_t)(m0 + srow) * 1024 + ((l15 ^ r7s) << 2);
    const float* gb1 = gb0 + (size_t)128 * 1024;
    const int so = wave * 256;                // f32; + H*8192 + Q*2048

    // ---- ds_read swizzled f32 offsets within a row (c16 = kk*8+lkg*2+h16)
    const int rbase = (wr * 128 + l15) * 64;  // + mf*1024
    const int s00 = ((lkg * 2 + 0) ^ (l15 & 7)) << 2;
    const int s01 = ((lkg * 2 + 1) ^ (l15 & 7)) << 2;
    const int s10 = ((8 + lkg * 2 + 0) ^ (l15 & 7)) << 2;
    const int s11 = ((8 + lkg * 2 + 1) ^ (l15 & 7)) << 2;

    const unsigned short* wB = WebfB + (size_t)ct * 262144 + lane * 8;

    f32x4 acc[8][4];
#pragma unroll
    for (int mf = 0; mf < 8; ++mf)
#pragma unroll
        for (int nf = 0; nf < 4; ++nf) acc[mf][nf] = (f32x4){0.f, 0.f, 0.f, 0.f};

    bf16x8 bA[8], bB[8];

#define STG(H, Q, SB, TILE)                                                    \
    __builtin_amdgcn_global_load_lds(                                          \
        (g_u32*)(((H) ? gb1 : gb0) + (size_t)(Q) * 32768 + (TILE) * 64),       \
        (lds_u32*)((SB) + (H) * 8192 + (Q) * 2048 + so), 16, 0, 0)

#define LOADB(I, BR)                                                           \
    do {                                                                       \
        _Pragma("unroll")                                                      \
        for (int kk = 0; kk < 2; ++kk)                                         \
            _Pragma("unroll")                                                  \
            for (int nf = 0; nf < 4; ++nf)                                     \
                BR[kk * 4 + nf] = *(const bf16x8*)(                            \
                    wB + (size_t)(((I) * 2 + kk) * 16 + wc * 4 + nf) * 512);   \
    } while (0)

// one phase: mf pair (MF0, MF0+1); STAGE_CODE between ds_read and barrier.
#define PHASE(MF0, RB, BCUR, STAGE_CODE, PRE_BAR)                              \
    do {                                                                       \
        const float* p0 = (RB) + rbase + (MF0) * 1024;                         \
        const float* p1 = p0 + 1024;                                           \
        float4 v0 = *(const float4*)(p0 + s00);                                \
        float4 v1 = *(const float4*)(p0 + s01);                                \
        float4 v2 = *(const float4*)(p0 + s10);                                \
        float4 v3 = *(const float4*)(p0 + s11);                                \
        float4 v4 = *(const float4*)(p1 + s00);                                \
        float4 v5 = *(const float4*)(p1 + s01);                                \
        float4 v6 = *(const float4*)(p1 + s10);                                \
        float4 v7 = *(const float4*)(p1 + s11);                                \
        STAGE_CODE;                                                            \
        PRE_BAR;                                                               \
        __builtin_amdgcn_s_barrier();                                          \
        union { unsigned u[4]; bf16x8 v; } a00, a01, a10, a11;                 \
        a00.u[0] = pk2(v0.x, v0.y); a00.u[1] = pk2(v0.z, v0.w);                \
        a00.u[2] = pk2(v1.x, v1.y); a00.u[3] = pk2(v1.z, v1.w);                \
        a01.u[0] = pk2(v2.x, v2.y); a01.u[1] = pk2(v2.z, v2.w);                \
        a01.u[2] = pk2(v3.x, v3.y); a01.u[3] = pk2(v3.z, v3.w);                \
        a10.u[0] = pk2(v4.x, v4.y); a10.u[1] = pk2(v4.z, v4.w);                \
        a10.u[2] = pk2(v5.x, v5.y); a10.u[3] = pk2(v5.z, v5.w);                \
        a11.u[0] = pk2(v6.x, v6.y); a11.u[1] = pk2(v6.z, v6.w);                \
        a11.u[2] = pk2(v7.x, v7.y); a11.u[3] = pk2(v7.z, v7.w);                \
        PRIO1;                                                                 \
        _Pragma("unroll")                                                      \
        for (int nf = 0; nf < 4; ++nf) {                                       \
            acc[MF0][nf] = __builtin_amdgcn_mfma_f32_16x16x32_bf16(            \
                a00.v, BCUR[nf], acc[MF0][nf], 0, 0, 0);                       \
            acc[MF0][nf] = __builtin_amdgcn_mfma_f32_16x16x32_bf16(            \
                a01.v, BCUR[4 + nf], acc[MF0][nf], 0, 0, 0);                   \
            acc[(MF0) + 1][nf] = __builtin_amdgcn_mfma_f32_16x16x32_bf16(      \
                a10.v, BCUR[nf], acc[(MF0) + 1][nf], 0, 0, 0);                 \
            acc[(MF0) + 1][nf] = __builtin_amdgcn_mfma_f32_16x16x32_bf16(      \
                a11.v, BCUR[4 + nf], acc[(MF0) + 1][nf], 0, 0, 0);             \
        }                                                                      \
        PRIO0;                                                                 \
        __builtin_amdgcn_s_barrier();                                          \
    } while (0)

#define VMC8() do { asm volatile("s_waitcnt vmcnt(8)" ::: "memory"); SB0(); } while (0)

#define DO_TILE(I, RB, SB, BCUR, BNXT)                                         \
    do {                                                                       \
        PHASE(0, RB, BCUR, { STG(0, 0, SB, (I) + 1); STG(0, 1, SB, (I) + 1); }, {}); \
        PHASE(2, RB, BCUR, { STG(0, 2, SB, (I) + 1); STG(0, 3, SB, (I) + 1); }, {}); \
        PHASE(4, RB, BCUR, { STG(1, 0, SB, (I) + 1); STG(1, 1, SB, (I) + 1); }, {}); \
        PHASE(6, RB, BCUR,                                                     \
              { STG(1, 2, SB, (I) + 1); STG(1, 3, SB, (I) + 1);                \
                LOADB((I) + 1, BNXT); },                                       \
              VMC8());                                                         \
    } while (0)

#define DO_TILE_LAST(RB, BCUR)                                                 \
    do {                                                                       \
        PHASE(0, RB, BCUR, {}, {});                                            \
        PHASE(2, RB, BCUR, {}, {});                                            \
        PHASE(4, RB, BCUR, {}, {});                                            \
        PHASE(6, RB, BCUR, {}, {});                                            \
    } while (0)

    // prologue: stage tile 0 (8 issues) THEN B(0) (so vmcnt(8) retires stages)
    STG(0, 0, buf0, 0); STG(0, 1, buf0, 0); STG(0, 2, buf0, 0); STG(0, 3, buf0, 0);
    STG(1, 0, buf0, 0); STG(1, 1, buf0, 0); STG(1, 2, buf0, 0); STG(1, 3, buf0, 0);
    LOADB(0, bA);
    VMC8();
    __builtin_amdgcn_s_barrier();

#pragma unroll 1
    for (int k2 = 0; k2 < 7; ++k2) {
        DO_TILE(2 * k2,     buf0, buf1, bA, bB);
        DO_TILE(2 * k2 + 1, buf1, buf0, bB, bA);
    }
    DO_TILE(14, buf0, buf1, bA, bB);   // stages tile 15 into buf1, B15 -> bB
    DO_TILE_LAST(buf1, bB);

    // epilogue: tanh + dot Wv over this wave's 64 cols (rows wr*128 .. +127)
    float sWv[4], wvv[4];
#pragma unroll
    for (int nf = 0; nf < 4; ++nf) {
        int col = ct * 256 + wc * 64 + nf * 16 + l15;
        sWv[nf] = sW[(b << 9) + col];
        wvv[nf] = Wv[col];
    }
    float pa[8][4];
#pragma unroll
    for (int mf = 0; mf < 8; ++mf) {
#pragma unroll
        for (int r = 0; r < 4; ++r) pa[mf][r] = 0.f;
#pragma unroll
        for (int nf = 0; nf < 4; ++nf)
#pragma unroll
            for (int r = 0; r < 4; ++r)
                pa[mf][r] += fast_tanh(acc[mf][nf][r] + sWv[nf]) * wvv[nf];
    }
#pragma unroll
    for (int m = 1; m < 16; m <<= 1)
#pragma unroll
        for (int mf = 0; mf < 8; ++mf)
#pragma unroll
            for (int r = 0; r < 4; ++r)
                pa[mf][r] += __shfl_xor(pa[mf][r], m, 64);

    if (l15 == 0) {
#pragma unroll
        for (int mf = 0; mf < 8; ++mf)
#pragma unroll
            for (int r = 0; r < 4; ++r)
                lred[wave][mf * 16 + lkg * 4 + r] = pa[mf][r];
    }
    __syncthreads();
    if (t < 256) {
        int wrh = t >> 7, row = t & 127;
        float ssum = (lred[wrh * 4 + 0][row] + lred[wrh * 4 + 1][row]) +
                     (lred[wrh * 4 + 2][row] + lred[wrh * 4 + 3][row]);
        attpart[(size_t)ct * 65536 + m0 + wrh * 128 + row] = ssum;
    }
#undef STG
#undef LOADB
#undef PHASE
#undef VMC8
#undef DO_TILE
#undef DO_TILE_LAST
}

// ---------------- softmax over S=2048 per batch row (sums 2 col partials) ---
__global__ __launch_bounds__(256) void softmax_kernel(const float* __restrict__ attpart,
                                                      float* __restrict__ out) {
    int b = blockIdx.x, t = threadIdx.x;
    float v[8];
#pragma unroll
    for (int i = 0; i < 8; ++i) {
        int idx = b * 2048 + t + 256 * i;
        v[i] = attpart[idx] + attpart[65536 + idx];
    }
    float mx = v[0];
#pragma unroll
    for (int i = 1; i < 8; ++i) mx = fmaxf(mx, v[i]);
#pragma unroll
    for (int m = 1; m < 64; m <<= 1) mx = fmaxf(mx, __shfl_xor(mx, m, 64));
    __shared__ float redm[4], reds[4];
    if ((t & 63) == 0) redm[t >> 6] = mx;
    __syncthreads();
    mx = fmaxf(fmaxf(redm[0], redm[1]), fmaxf(redm[2], redm[3]));
    float sum = 0.f;
#pragma unroll
    for (int i = 0; i < 8; ++i) { v[i] = __expf(v[i] - mx); sum += v[i]; }
#pragma unroll
    for (int m = 1; m < 64; m <<= 1) sum += __shfl_xor(sum, m, 64);
    if ((t & 63) == 0) reds[t >> 6] = sum;
    __syncthreads();
    sum = reds[0] + reds[1] + reds[2] + reds[3];
    float inv = 1.0f / sum;
    float* soft = out + 32768;
#pragma unroll
    for (int i = 0; i < 8; ++i) soft[b * 2048 + t + 256 * i] = v[i] * inv;
}

// ---------------- context partial: 16 chunks of 128 rows per batch ----------
__global__ __launch_bounds__(256) void ctx_partial(const float* __restrict__ enc,
                                                   const float* __restrict__ soft,
                                                   float* __restrict__ part) {
    int blk = blockIdx.x;               // b*16 + chunk
    int b = blk >> 4, s0 = (blk & 15) * 128;
    int t = threadIdx.x;
    float4 a = {0.f, 0.f, 0.f, 0.f};
    const float* base = enc + ((size_t)(b * 2048 + s0)) * 1024 + t * 4;
    const float* sw = soft + b * 2048 + s0;
#pragma unroll 4
    for (int s = 0; s < 128; ++s) {
        float w = sw[s];
        float4 e = *(const float4*)(base + (size_t)s * 1024);
        a.x += w * e.x; a.y += w * e.y; a.z += w * e.z; a.w += w * e.w;
    }
    *(float4*)(part + (size_t)blk * 1024 + t * 4) = a;
}

__global__ __launch_bounds__(256) void ctx_reduce(const float* __restrict__ part,
                                                  float* __restrict__ ctx) {
    int id = blockIdx.x * 256 + threadIdx.x;  // 32768 = 32b * 1024e
    int b = id >> 10, e = id & 1023;
    float s = 0.f;
#pragma unroll 8
    for (int c = 0; c < 16; ++c) s += part[((size_t)(b * 16 + c)) * 1024 + e];
    ctx[id] = s;
}

extern "C" void kernel_launch(void* const* d_in, const int* in_sizes, int n_in,
                              void* d_out, int out_size, void* d_ws, size_t ws_size,
                              hipStream_t stream) {
    const float* s   = (const float*)d_in[0];
    const float* enc = (const float*)d_in[1];
    const float* Wat = (const float*)d_in[2];
    const float* Wv  = (const float*)d_in[3];
    float* out = (float*)d_out;

    char* ws = (char*)d_ws;
    float* sW             = (float*)ws;                                   // 64 KiB
    unsigned short* WebfB = (unsigned short*)(ws + (64 << 10));           // 1 MiB
    float* attpart        = (float*)(ws + (64 << 10) + (1 << 20));        // 512 KiB
    float* part           = (float*)(ws + (64 << 10) + (1 << 20) + (512 << 10)); // 2 MiB

    prep_sw<<<64, 256, 0, stream>>>(s, Wat, sW);
    prep_weB<<<256, 256, 0, stream>>>(Wat, WebfB);
    energy_kernel<<<512, 512, 0, stream>>>(enc, WebfB, sW, Wv, attpart);
    softmax_kernel<<<32, 256, 0, stream>>>(attpart, out);
    ctx_partial<<<512, 256, 0, stream>>>(enc, out + 32768, part);
    ctx_reduce<<<128, 256, 0, stream>>>(part, out);
}

// Round 14
// 192.298 us; speedup vs baseline: 1.7990x; 1.0776x over previous
//
#include <hip/hip_runtime.h>
#include <hip/hip_bf16.h>

// Attention head: context/softmax over (B=32, S=2048, DEC=512, ENC2=1024)
// d_in[0] = s (1,32,512) f32 | d_in[1] = enc (32,2048,1024) f32
// d_in[2] = W_attn (512,1536) f32 | d_in[3] = W_v (1,512) f32
// d_out = context (32,1024) f32 ++ soft (32,2048) f32

typedef __attribute__((ext_vector_type(8))) short bf16x8;
typedef __attribute__((ext_vector_type(4))) float f32x4;
typedef __attribute__((address_space(3))) unsigned lds_u32;
typedef const __attribute__((address_space(1))) unsigned g_u32;

#define SB0() __builtin_amdgcn_sched_barrier(0)
#define PRIO1 __builtin_amdgcn_s_setprio(1)
#define PRIO0 __builtin_amdgcn_s_setprio(0)

static __device__ __forceinline__ unsigned short f2bf(float f) {
    union { float f; unsigned u; } v; v.f = f;
    unsigned r = (v.u + 0x7fffu + ((v.u >> 16) & 1u)) >> 16;  // RNE
    return (unsigned short)r;
}

static __device__ __forceinline__ unsigned pk2(float x, float y) {
    union { __hip_bfloat162 h; unsigned u; } c;
    c.h = __float22bfloat162_rn(make_float2(x, y));  // v_cvt_pk_bf16_f32
    return c.u;
}

static __device__ __forceinline__ float fast_tanh(float x) {
    return 1.0f - 2.0f / (__expf(2.0f * x) + 1.0f);
}

// ---------------- prep: sW[b,h] = sum_d s[b,d] * W_attn[h, d] ----------------
__global__ __launch_bounds__(256) void prep_sw(const float* __restrict__ s,
                                               const float* __restrict__ Wat,
                                               float* __restrict__ sW) {
    int id = blockIdx.x * 256 + threadIdx.x;   // 16384 = 32b * 512h
    int b = id >> 9, h = id & 511;
    const float4* wr = (const float4*)(Wat + (size_t)h * 1536);
    const float4* sr = (const float4*)(s + (size_t)b * 512);
    float acc = 0.f;
#pragma unroll 8
    for (int i = 0; i < 128; ++i) {
        float4 w = wr[i], sv = sr[i];
        acc += w.x * sv.x + w.y * sv.y + w.z * sv.z + w.w * sv.w;
    }
    sW[id] = acc;
}

// ------- prep: WebfB fragment-major bf16 repack of W_e = W_attn[:,512:] -----
// g = ct*512 + step*32 + kk*16 + wc*4 + nf   (g = tid>>6, g < 1024)
// element = W_e[col = ct*256+wc*64+nf*16+(lane&15)][k = step*64+kk*32+(lane>>4)*8+j]
__global__ __launch_bounds__(256) void prep_weB(const float* __restrict__ Wat,
                                                unsigned short* __restrict__ WebfB) {
    int tid = blockIdx.x * 256 + threadIdx.x;  // 0..65535 (grid 256)
    int lane = tid & 63;
    int g = tid >> 6;
    int nf = g & 3, wc = (g >> 2) & 3, kk = (g >> 4) & 1, step = (g >> 5) & 15, ct = (g >> 9) & 1;
    int col = ct * 256 + wc * 64 + nf * 16 + (lane & 15);
    int k0 = step * 64 + kk * 32 + (lane >> 4) * 8;
    const float* src = Wat + (size_t)col * 1536 + 512 + k0;
    float4 w0 = *(const float4*)src;
    float4 w1 = *(const float4*)(src + 4);
    union { unsigned short us[8]; int4 v; } p;
    p.us[0] = f2bf(w0.x); p.us[1] = f2bf(w0.y); p.us[2] = f2bf(w0.z); p.us[3] = f2bf(w0.w);
    p.us[4] = f2bf(w1.x); p.us[5] = f2bf(w1.y); p.us[6] = f2bf(w1.z); p.us[7] = f2bf(w1.w);
    *(int4*)(WebfB + (size_t)tid * 8) = p.v;
}

// ---------------- energy: attpart[ct][m] = sum_{256 cols} tanh(..)*Wv --------
// Block 64r x 256c, 256 thr, 4 waves (wc 0..3), wave 64x64. Grid 2048,
// (bid, bid+8) ct-pair on same XCD (R5-validated FETCH-neutral).
// A: f32 in LDS, FRAGMENT-MAJOR (16 regions x 1KB per 64-k tile): stage via
// 16 global_load_lds, read at lane*16 contiguous -> zero conflicts by
// construction. 3 LDS buffers, counted vmcnt(12) (never 0 in loop), one raw
// s_barrier per step. B: register DOUBLE-buffer, LOADB(i+1) issued before
// stage(i+2) so B-waits never transitively wait on HBM. setprio on MFMA.
__global__ __launch_bounds__(256, 3) void energy_kernel(
    const float* __restrict__ enc, const unsigned short* __restrict__ WebfB,
    const float* __restrict__ sW, const float* __restrict__ Wv,
    float* __restrict__ attpart) {
    __shared__ __align__(16) char lA[3][16384];   // 3 x 16KB fragment-major A
    __shared__ float lred[4][64];

    const int t = threadIdx.x;         // 0..255
    const int lane = t & 63;
    const int wc = t >> 6;             // wave = col quarter 0..3
    const int bid = blockIdx.x;
    const int ct = (bid >> 3) & 1;                   // col half of 512
    const int rt = (bid & 7) | ((bid >> 4) << 3);    // row tile 0..1023
    const int m0 = rt * 64;
    const int b = m0 >> 11;
    const int l15 = lane & 15;
    const int lkg = lane >> 4;

    // staging: call q covers region r = q*4 + wc; r = kk*8 + mf*2 + h
    // lane writes 16B = A[m0 + mf*16 + l15][step*64 + kk*32 + lkg*8 + h*4 ..+3]
    const float* gq[4];
    int ro[4];
#pragma unroll
    for (int q = 0; q < 4; ++q) {
        int r = q * 4 + wc;
        int mf = (r >> 1) & 3, kk = r >> 3, h = r & 1;
        gq[q] = enc + (size_t)(m0 + mf * 16 + l15) * 1024 + kk * 32 + lkg * 8 + h * 4;
        ro[q] = r * 1024;             // byte offset of region (HW adds lane*16)
    }

    const unsigned short* wB = WebfB + (size_t)ct * 262144 + lane * 8;

    f32x4 acc[4][4];
#pragma unroll
    for (int mf = 0; mf < 4; ++mf)
#pragma unroll
        for (int nf = 0; nf < 4; ++nf) acc[mf][nf] = (f32x4){0.f, 0.f, 0.f, 0.f};

    bf16x8 bfrA[8], bfrB[8];

#define STAGE(STEP, BUF)                                                       \
    do {                                                                       \
        _Pragma("unroll")                                                      \
        for (int q = 0; q < 4; ++q)                                            \
            __builtin_amdgcn_global_load_lds((g_u32*)(gq[q] + (STEP) * 64),    \
                                             (lds_u32*)((BUF) + ro[q]), 16, 0, 0); \
    } while (0)

#define LOADB(I, BR)                                                           \
    do {                                                                       \
        _Pragma("unroll")                                                      \
        for (int kk = 0; kk < 2; ++kk)                                         \
            _Pragma("unroll")                                                  \
            for (int nf = 0; nf < 4; ++nf)                                     \
                BR[kk * 4 + nf] = *(const bf16x8*)(                            \
                    wB + (size_t)(((I) * 2 + kk) * 16 + wc * 4 + nf) * 512);   \
    } while (0)

#define COMP(BUF, BR)                                                          \
    do {                                                                       \
        const char* rb = (const char*)(BUF) + lane * 16;                       \
        _Pragma("unroll")                                                      \
        for (int kk = 0; kk < 2; ++kk) {                                       \
            _Pragma("unroll")                                                  \
            for (int mf = 0; mf < 4; ++mf) {                                   \
                float4 h0 = *(const float4*)(rb + (kk * 8 + mf * 2) * 1024);   \
                float4 h1 = *(const float4*)(rb + (kk * 8 + mf * 2) * 1024 + 1024); \
                union { unsigned u[4]; bf16x8 v; } af;                         \
                af.u[0] = pk2(h0.x, h0.y); af.u[1] = pk2(h0.z, h0.w);          \
                af.u[2] = pk2(h1.x, h1.y); af.u[3] = pk2(h1.z, h1.w);          \
                _Pragma("unroll")                                              \
                for (int nf = 0; nf < 4; ++nf)                                 \
                    acc[mf][nf] = __builtin_amdgcn_mfma_f32_16x16x32_bf16(     \
                        af.v, BR[kk * 4 + nf], acc[mf][nf], 0, 0, 0);          \
            }                                                                  \
        }                                                                      \
    } while (0)

#define VM(N) do { asm volatile("s_waitcnt vmcnt(" #N ")" ::: "memory"); SB0(); } while (0)

    char* p0 = lA[0];
    char* p1 = lA[1];
    char* p2 = lA[2];

    // prologue: stage(0), B(0), stage(1) -> queue [A0:4][B0:8][A1:4]
    STAGE(0, p0); SB0();
    LOADB(0, bfrA); SB0();
    STAGE(1, p1); SB0();

#pragma unroll 1
    for (int k = 0; k < 7; ++k) {
        const int i = 2 * k;
        // even step i: consumes bfrA, tile in p0
        VM(12);                              // A(i) resident
        __builtin_amdgcn_s_barrier();
        LOADB(i + 1, bfrB); SB0();           // B before younger A stages
        STAGE(i + 2, p2); SB0();
        PRIO1; COMP(p0, bfrA); PRIO0;
        { char* tp = p0; p0 = p1; p1 = p2; p2 = tp; }
        // odd step i+1: consumes bfrB
        VM(12);
        __builtin_amdgcn_s_barrier();
        LOADB(i + 2, bfrA); SB0();
        STAGE(i + 3, p2); SB0();
        PRIO1; COMP(p0, bfrB); PRIO0;
        { char* tp = p0; p0 = p1; p1 = p2; p2 = tp; }
    }
    // step 14 (even, bfrA): no stage(16)
    VM(12);
    __builtin_amdgcn_s_barrier();
    LOADB(15, bfrB); SB0();
    PRIO1; COMP(p0, bfrA); PRIO0;
    { char* tp = p0; p0 = p1; p1 = p2; p2 = tp; }
    // step 15 (odd, bfrB): queue = [A15:4][B15:8] -> retire A15
    VM(8);
    __builtin_amdgcn_s_barrier();
    PRIO1; COMP(p0, bfrB); PRIO0;

    // epilogue: tanh + dot Wv over this wave's 64 cols
    float sWv[4], wvv[4];
#pragma unroll
    for (int nf = 0; nf < 4; ++nf) {
        int col = ct * 256 + wc * 64 + nf * 16 + l15;
        sWv[nf] = sW[(b << 9) + col];
        wvv[nf] = Wv[col];
    }
    float pa[4][4];
#pragma unroll
    for (int mf = 0; mf < 4; ++mf) {
#pragma unroll
        for (int r = 0; r < 4; ++r) pa[mf][r] = 0.f;
#pragma unroll
        for (int nf = 0; nf < 4; ++nf)
#pragma unroll
            for (int r = 0; r < 4; ++r)
                pa[mf][r] += fast_tanh(acc[mf][nf][r] + sWv[nf]) * wvv[nf];
    }
#pragma unroll
    for (int m = 1; m < 16; m <<= 1)
#pragma unroll
        for (int mf = 0; mf < 4; ++mf)
#pragma unroll
            for (int r = 0; r < 4; ++r)
                pa[mf][r] += __shfl_xor(pa[mf][r], m, 64);

    if (l15 == 0) {
#pragma unroll
        for (int mf = 0; mf < 4; ++mf)
#pragma unroll
            for (int r = 0; r < 4; ++r)
                lred[wc][mf * 16 + lkg * 4 + r] = pa[mf][r];
    }
    __syncthreads();
    if (t < 64) {
        attpart[(size_t)ct * 65536 + m0 + t] =
            (lred[0][t] + lred[1][t]) + (lred[2][t] + lred[3][t]);
    }
#undef STAGE
#undef LOADB
#undef COMP
#undef VM
}

// ---------------- softmax over S=2048 per batch row (sums 2 col partials) ---
__global__ __launch_bounds__(256) void softmax_kernel(const float* __restrict__ attpart,
                                                      float* __restrict__ out) {
    int b = blockIdx.x, t = threadIdx.x;
    float v[8];
#pragma unroll
    for (int i = 0; i < 8; ++i) {
        int idx = b * 2048 + t + 256 * i;
        v[i] = attpart[idx] + attpart[65536 + idx];
    }
    float mx = v[0];
#pragma unroll
    for (int i = 1; i < 8; ++i) mx = fmaxf(mx, v[i]);
#pragma unroll
    for (int m = 1; m < 64; m <<= 1) mx = fmaxf(mx, __shfl_xor(mx, m, 64));
    __shared__ float redm[4], reds[4];
    if ((t & 63) == 0) redm[t >> 6] = mx;
    __syncthreads();
    mx = fmaxf(fmaxf(redm[0], redm[1]), fmaxf(redm[2], redm[3]));
    float sum = 0.f;
#pragma unroll
    for (int i = 0; i < 8; ++i) { v[i] = __expf(v[i] - mx); sum += v[i]; }
#pragma unroll
    for (int m = 1; m < 64; m <<= 1) sum += __shfl_xor(sum, m, 64);
    if ((t & 63) == 0) reds[t >> 6] = sum;
    __syncthreads();
    sum = reds[0] + reds[1] + reds[2] + reds[3];
    float inv = 1.0f / sum;
    float* soft = out + 32768;
#pragma unroll
    for (int i = 0; i < 8; ++i) soft[b * 2048 + t + 256 * i] = v[i] * inv;
}

// ---------------- context partial: 16 chunks of 128 rows per batch ----------
__global__ __launch_bounds__(256) void ctx_partial(const float* __restrict__ enc,
                                                   const float* __restrict__ soft,
                                                   float* __restrict__ part) {
    int blk = blockIdx.x;               // b*16 + chunk
    int b = blk >> 4, s0 = (blk & 15) * 128;
    int t = threadIdx.x;
    float4 a = {0.f, 0.f, 0.f, 0.f};
    const float* base = enc + ((size_t)(b * 2048 + s0)) * 1024 + t * 4;
    const float* sw = soft + b * 2048 + s0;
#pragma unroll 4
    for (int s = 0; s < 128; ++s) {
        float w = sw[s];
        float4 e = *(const float4*)(base + (size_t)s * 1024);
        a.x += w * e.x; a.y += w * e.y; a.z += w * e.z; a.w += w * e.w;
    }
    *(float4*)(part + (size_t)blk * 1024 + t * 4) = a;
}

__global__ __launch_bounds__(256) void ctx_reduce(const float* __restrict__ part,
                                                  float* __restrict__ ctx) {
    int id = blockIdx.x * 256 + threadIdx.x;  // 32768 = 32b * 1024e
    int b = id >> 10, e = id & 1023;
    float s = 0.f;
#pragma unroll 8
    for (int c = 0; c < 16; ++c) s += part[((size_t)(b * 16 + c)) * 1024 + e];
    ctx[id] = s;
}

extern "C" void kernel_launch(void* const* d_in, const int* in_sizes, int n_in,
                              void* d_out, int out_size, void* d_ws, size_t ws_size,
                              hipStream_t stream) {
    const float* s   = (const float*)d_in[0];
    const float* enc = (const float*)d_in[1];
    const float* Wat = (const float*)d_in[2];
    const float* Wv  = (const float*)d_in[3];
    float* out = (float*)d_out;

    char* ws = (char*)d_ws;
    float* sW             = (float*)ws;                                   // 64 KiB
    unsigned short* WebfB = (unsigned short*)(ws + (64 << 10));           // 1 MiB
    float* attpart        = (float*)(ws + (64 << 10) + (1 << 20));        // 512 KiB
    float* part           = (float*)(ws + (64 << 10) + (1 << 20) + (512 << 10)); // 2 MiB

    prep_sw<<<64, 256, 0, stream>>>(s, Wat, sW);
    prep_weB<<<256, 256, 0, stream>>>(Wat, WebfB);
    energy_kernel<<<2048, 256, 0, stream>>>(enc, WebfB, sW, Wv, attpart);
    softmax_kernel<<<32, 256, 0, stream>>>(attpart, out);
    ctx_partial<<<512, 256, 0, stream>>>(enc, out + 32768, part);
    ctx_reduce<<<128, 256, 0, stream>>>(part, out);
}

// Round 15
// 190.522 us; speedup vs baseline: 1.8157x; 1.0093x over previous
//
#include <hip/hip_runtime.h>
#include <hip/hip_bf16.h>

// Attention head: context/softmax over (B=32, S=2048, DEC=512, ENC2=1024)
// d_in[0] = s (1,32,512) f32 | d_in[1] = enc (32,2048,1024) f32
// d_in[2] = W_attn (512,1536) f32 | d_in[3] = W_v (1,512) f32
// d_out = context (32,1024) f32 ++ soft (32,2048) f32

typedef __attribute__((ext_vector_type(8))) short bf16x8;
typedef __attribute__((ext_vector_type(4))) float f32x4;
typedef __attribute__((address_space(3))) unsigned lds_u32;
typedef const __attribute__((address_space(1))) unsigned g_u32;

#define SB0() __builtin_amdgcn_sched_barrier(0)
#define PRIO1 __builtin_amdgcn_s_setprio(1)
#define PRIO0 __builtin_amdgcn_s_setprio(0)

static __device__ __forceinline__ unsigned short f2bf(float f) {
    union { float f; unsigned u; } v; v.f = f;
    unsigned r = (v.u + 0x7fffu + ((v.u >> 16) & 1u)) >> 16;  // RNE
    return (unsigned short)r;
}

static __device__ __forceinline__ unsigned pk2(float x, float y) {
    union { __hip_bfloat162 h; unsigned u; } c;
    c.h = __float22bfloat162_rn(make_float2(x, y));  // v_cvt_pk_bf16_f32
    return c.u;
}

static __device__ __forceinline__ float fast_tanh(float x) {
    return 1.0f - 2.0f / (__expf(2.0f * x) + 1.0f);
}

// ---------------- prep: sW[b,h] = sum_d s[b,d] * W_attn[h, d] ----------------
__global__ __launch_bounds__(256) void prep_sw(const float* __restrict__ s,
                                               const float* __restrict__ Wat,
                                               float* __restrict__ sW) {
    int id = blockIdx.x * 256 + threadIdx.x;   // 16384 = 32b * 512h
    int b = id >> 9, h = id & 511;
    const float4* wr = (const float4*)(Wat + (size_t)h * 1536);
    const float4* sr = (const float4*)(s + (size_t)b * 512);
    float acc = 0.f;
#pragma unroll 8
    for (int i = 0; i < 128; ++i) {
        float4 w = wr[i], sv = sr[i];
        acc += w.x * sv.x + w.y * sv.y + w.z * sv.z + w.w * sv.w;
    }
    sW[id] = acc;
}

// ------- prep: WebfB fragment-major bf16 repack of W_e = W_attn[:,512:] -----
// g = ct*512 + step*32 + kk*16 + wc*4 + nf   (g = tid>>6, g < 1024)
// element = W_e[col = ct*256+wc*64+nf*16+(lane&15)][k = step*64+kk*32+(lane>>4)*8+j]
// -> per (ct,step): one contiguous 32 KB panel.
__global__ __launch_bounds__(256) void prep_weB(const float* __restrict__ Wat,
                                                unsigned short* __restrict__ WebfB) {
    int tid = blockIdx.x * 256 + threadIdx.x;  // 0..65535 (grid 256)
    int lane = tid & 63;
    int g = tid >> 6;
    int nf = g & 3, wc = (g >> 2) & 3, kk = (g >> 4) & 1, step = (g >> 5) & 15, ct = (g >> 9) & 1;
    int col = ct * 256 + wc * 64 + nf * 16 + (lane & 15);
    int k0 = step * 64 + kk * 32 + (lane >> 4) * 8;
    const float* src = Wat + (size_t)col * 1536 + 512 + k0;
    float4 w0 = *(const float4*)src;
    float4 w1 = *(const float4*)(src + 4);
    union { unsigned short us[8]; int4 v; } p;
    p.us[0] = f2bf(w0.x); p.us[1] = f2bf(w0.y); p.us[2] = f2bf(w0.z); p.us[3] = f2bf(w0.w);
    p.us[4] = f2bf(w1.x); p.us[5] = f2bf(w1.y); p.us[6] = f2bf(w1.z); p.us[7] = f2bf(w1.w);
    *(int4*)(WebfB + (size_t)tid * 8) = p.v;
}

// ---------------- energy: attpart[ct][m] = sum_{256 cols} tanh(..)*Wv --------
// Block 64r x 256c, 256 thr, 4 waves (wc 0..3), wave 64x64. Grid 2048,
// (bid, bid+8) ct-pair on same XCD. R8 structure with ONE change:
// B staged into LDS via global_load_lds (sink-proof; no dest register),
// issued FIRST each step so B-retirement never waits on younger A HBM loads.
// A: reg-staged 1-deep, cvt -> XOR-swizzled bf16 LDS (R8-verbatim, 0-conflict).
// Counted vmcnt(4) before each barrier (retire B(i+1), keep A-plain in flight).
// COMP = pure 16x ds_read_b128 + 32 MFMA (no cvt on MFMA path).
__global__ __launch_bounds__(256, 2) void energy_kernel(
    const float* __restrict__ enc, const unsigned short* __restrict__ WebfB,
    const float* __restrict__ sW, const float* __restrict__ Wv,
    float* __restrict__ attpart) {
    __shared__ __align__(16) char smem[81920];   // 80 KB exactly -> 2 blocks/CU
    unsigned short* lT0 = (unsigned short*)smem;          // 8 KB A bf16
    unsigned short* lT1 = (unsigned short*)(smem + 8192); // 8 KB
    char* Bb0 = smem + 16384;                             // 32 KB B
    char* Bb1 = smem + 49152;                             // 32 KB
    float* lred = (float*)smem;    // aliased over lT0 (free in epilogue)

    const int t = threadIdx.x;         // 0..255
    const int lane = t & 63;
    const int wc = t >> 6;             // wave = col quarter 0..3
    const int bid = blockIdx.x;
    const int ct = (bid >> 3) & 1;                   // col half of 512
    const int rt = (bid & 7) | ((bid >> 4) << 3);    // row tile 0..1023
    const int m0 = rt * 64;
    const int b = m0 >> 11;
    const int l15 = lane & 15;
    const int lkg = lane >> 4;

    // A staging (R8-verbatim): thread t covers rows q*16+(t>>4), f32 chunk t&15
    const int arow = t >> 4;           // 0..15
    const int achk = t & 15;
    const float* aptr = enc + (size_t)(m0 + arow) * 1024 + achk * 4;
    const int wsw = (((achk >> 1) ^ (arow & 7)) << 4) | ((achk & 1) << 3);

    // A ds_read (R8-verbatim): row = mf*16+l15
    const int rrowbase = l15 * 128;
    const int rsw0 = (lkg ^ (l15 & 7)) << 4;
    const int rsw1 = ((4 + lkg) ^ (l15 & 7)) << 4;

    // B panel base: per (ct, step) a contiguous 32 KB block
    const char* gB = (const char*)WebfB + (size_t)ct * 524288;

    f32x4 acc[4][4];
#pragma unroll
    for (int mf = 0; mf < 4; ++mf)
#pragma unroll
        for (int nf = 0; nf < 4; ++nf) acc[mf][nf] = (f32x4){0.f, 0.f, 0.f, 0.f};

    float4 azA[4], azB[4];

#define BSTAGE(I, BB)                                                          \
    do {                                                                       \
        _Pragma("unroll")                                                      \
        for (int q = 0; q < 8; ++q)                                            \
            __builtin_amdgcn_global_load_lds(                                  \
                (g_u32*)(gB + (size_t)(I) * 32768 + q * 4096 + wc * 1024 +     \
                         lane * 16),                                           \
                (lds_u32*)((BB) + q * 4096 + wc * 1024), 16, 0, 0);            \
    } while (0)

#define LOADA(S, AR)                                                           \
    do {                                                                       \
        _Pragma("unroll")                                                      \
        for (int q = 0; q < 4; ++q)                                            \
            AR[q] = *(const float4*)(aptr + (size_t)q * 16384 + (S) * 64);     \
    } while (0)

#define CVTW(AR, LT)                                                           \
    do {                                                                       \
        _Pragma("unroll")                                                      \
        for (int q = 0; q < 4; ++q) {                                          \
            uint2 wv;                                                          \
            wv.x = pk2(AR[q].x, AR[q].y);                                      \
            wv.y = pk2(AR[q].z, AR[q].w);                                      \
            *(uint2*)((char*)(LT) + (q * 16 + arow) * 128 + wsw) = wv;         \
        }                                                                      \
    } while (0)

#define COMP(LT, BB)                                                           \
    do {                                                                       \
        _Pragma("unroll")                                                      \
        for (int kk = 0; kk < 2; ++kk) {                                       \
            const int rs = kk ? rsw1 : rsw0;                                   \
            _Pragma("unroll")                                                  \
            for (int mf = 0; mf < 4; ++mf) {                                   \
                bf16x8 af = *(const bf16x8*)((const char*)(LT) + rrowbase +    \
                                             mf * 2048 + rs);                  \
                _Pragma("unroll")                                              \
                for (int nf = 0; nf < 4; ++nf) {                               \
                    bf16x8 bf = *(const bf16x8*)(                              \
                        (BB) + (kk * 16 + wc * 4 + nf) * 1024 + lane * 16);    \
                    acc[mf][nf] = __builtin_amdgcn_mfma_f32_16x16x32_bf16(     \
                        af, bf, acc[mf][nf], 0, 0, 0);                         \
                }                                                              \
            }                                                                  \
        }                                                                      \
    } while (0)

#define ENDSTEP(N)                                                             \
    do {                                                                       \
        asm volatile("s_waitcnt vmcnt(" #N ") lgkmcnt(0)" ::: "memory");       \
        SB0();                                                                 \
        __builtin_amdgcn_s_barrier();                                          \
    } while (0)

    // prologue: B(0)->Bb0 first; A(0),A(1)->regs; A(0) cvt to lT0
    BSTAGE(0, Bb0); SB0();
    LOADA(0, azA); SB0();
    LOADA(1, azB); SB0();
    CVTW(azA, lT0);
    ENDSTEP(4);                 // retire B(0)+A(0); A(1) stays in flight

#pragma unroll 1
    for (int k = 0; k < 7; ++k) {
        const int i = 2 * k;
        // even step i: COMP lT0/Bb0; stage B(i+1)->Bb1; load A(i+2); cvt A(i+1)->lT1
        BSTAGE(i + 1, Bb1); SB0();
        LOADA(i + 2, azA); SB0();
        CVTW(azB, lT1); SB0();
        PRIO1; COMP(lT0, Bb0); PRIO0;
        ENDSTEP(4);             // retire B(i+1); A(i+2) stays in flight
        // odd step i+1: COMP lT1/Bb1
        BSTAGE(i + 2, Bb0); SB0();
        LOADA(i + 3, azB); SB0();
        CVTW(azA, lT0); SB0();
        PRIO1; COMP(lT1, Bb1); PRIO0;
        ENDSTEP(4);
    }
    // step 14: COMP lT0/Bb0; stage B(15); cvt A(15)->lT1; no more A loads
    BSTAGE(15, Bb1); SB0();
    CVTW(azB, lT1); SB0();
    PRIO1; COMP(lT0, Bb0); PRIO0;
    ENDSTEP(0);                 // retire B(15); queue empty
    // step 15: COMP lT1/Bb1
    PRIO1; COMP(lT1, Bb1); PRIO0;

    // epilogue: tanh + dot Wv over this wave's 64 cols
    float sWv[4], wvv[4];
#pragma unroll
    for (int nf = 0; nf < 4; ++nf) {
        int col = ct * 256 + wc * 64 + nf * 16 + l15;
        sWv[nf] = sW[(b << 9) + col];
        wvv[nf] = Wv[col];
    }
    float pa[4][4];
#pragma unroll
    for (int mf = 0; mf < 4; ++mf) {
#pragma unroll
        for (int r = 0; r < 4; ++r) pa[mf][r] = 0.f;
#pragma unroll
        for (int nf = 0; nf < 4; ++nf)
#pragma unroll
            for (int r = 0; r < 4; ++r)
                pa[mf][r] += fast_tanh(acc[mf][nf][r] + sWv[nf]) * wvv[nf];
    }
#pragma unroll
    for (int m = 1; m < 16; m <<= 1)
#pragma unroll
        for (int mf = 0; mf < 4; ++mf)
#pragma unroll
            for (int r = 0; r < 4; ++r)
                pa[mf][r] += __shfl_xor(pa[mf][r], m, 64);

    __syncthreads();            // all COMP LDS reads done before lred aliasing
    if (l15 == 0) {
#pragma unroll
        for (int mf = 0; mf < 4; ++mf)
#pragma unroll
            for (int r = 0; r < 4; ++r)
                lred[wc * 64 + mf * 16 + lkg * 4 + r] = pa[mf][r];
    }
    __syncthreads();
    if (t < 64) {
        attpart[(size_t)ct * 65536 + m0 + t] =
            (lred[0 * 64 + t] + lred[1 * 64 + t]) +
            (lred[2 * 64 + t] + lred[3 * 64 + t]);
    }
#undef BSTAGE
#undef LOADA
#undef CVTW
#undef COMP
#undef ENDSTEP
}

// ---------------- softmax over S=2048 per batch row (sums 2 col partials) ---
__global__ __launch_bounds__(256) void softmax_kernel(const float* __restrict__ attpart,
                                                      float* __restrict__ out) {
    int b = blockIdx.x, t = threadIdx.x;
    float v[8];
#pragma unroll
    for (int i = 0; i < 8; ++i) {
        int idx = b * 2048 + t + 256 * i;
        v[i] = attpart[idx] + attpart[65536 + idx];
    }
    float mx = v[0];
#pragma unroll
    for (int i = 1; i < 8; ++i) mx = fmaxf(mx, v[i]);
#pragma unroll
    for (int m = 1; m < 64; m <<= 1) mx = fmaxf(mx, __shfl_xor(mx, m, 64));
    __shared__ float redm[4], reds[4];
    if ((t & 63) == 0) redm[t >> 6] = mx;
    __syncthreads();
    mx = fmaxf(fmaxf(redm[0], redm[1]), fmaxf(redm[2], redm[3]));
    float sum = 0.f;
#pragma unroll
    for (int i = 0; i < 8; ++i) { v[i] = __expf(v[i] - mx); sum += v[i]; }
#pragma unroll
    for (int m = 1; m < 64; m <<= 1) sum += __shfl_xor(sum, m, 64);
    if ((t & 63) == 0) reds[t >> 6] = sum;
    __syncthreads();
    sum = reds[0] + reds[1] + reds[2] + reds[3];
    float inv = 1.0f / sum;
    float* soft = out + 32768;
#pragma unroll
    for (int i = 0; i < 8; ++i) soft[b * 2048 + t + 256 * i] = v[i] * inv;
}

// ---------------- context partial: 16 chunks of 128 rows per batch ----------
__global__ __launch_bounds__(256) void ctx_partial(const float* __restrict__ enc,
                                                   const float* __restrict__ soft,
                                                   float* __restrict__ part) {
    int blk = blockIdx.x;               // b*16 + chunk
    int b = blk >> 4, s0 = (blk & 15) * 128;
    int t = threadIdx.x;
    float4 a = {0.f, 0.f, 0.f, 0.f};
    const float* base = enc + ((size_t)(b * 2048 + s0)) * 1024 + t * 4;
    const float* sw = soft + b * 2048 + s0;
#pragma unroll 4
    for (int s = 0; s < 128; ++s) {
        float w = sw[s];
        float4 e = *(const float4*)(base + (size_t)s * 1024);
        a.x += w * e.x; a.y += w * e.y; a.z += w * e.z; a.w += w * e.w;
    }
    *(float4*)(part + (size_t)blk * 1024 + t * 4) = a;
}

__global__ __launch_bounds__(256) void ctx_reduce(const float* __restrict__ part,
                                                  float* __restrict__ ctx) {
    int id = blockIdx.x * 256 + threadIdx.x;  // 32768 = 32b * 1024e
    int b = id >> 10, e = id & 1023;
    float s = 0.f;
#pragma unroll 8
    for (int c = 0; c < 16; ++c) s += part[((size_t)(b * 16 + c)) * 1024 + e];
    ctx[id] = s;
}

extern "C" void kernel_launch(void* const* d_in, const int* in_sizes, int n_in,
                              void* d_out, int out_size, void* d_ws, size_t ws_size,
                              hipStream_t stream) {
    const float* s   = (const float*)d_in[0];
    const float* enc = (const float*)d_in[1];
    const float* Wat = (const float*)d_in[2];
    const float* Wv  = (const float*)d_in[3];
    float* out = (float*)d_out;

    char* ws = (char*)d_ws;
    float* sW             = (float*)ws;                                   // 64 KiB
    unsigned short* WebfB = (unsigned short*)(ws + (64 << 10));           // 1 MiB
    float* attpart        = (float*)(ws + (64 << 10) + (1 << 20));        // 512 KiB
    float* part           = (float*)(ws + (64 << 10) + (1 << 20) + (512 << 10)); // 2 MiB

    prep_sw<<<64, 256, 0, stream>>>(s, Wat, sW);
    prep_weB<<<256, 256, 0, stream>>>(Wat, WebfB);
    energy_kernel<<<2048, 256, 0, stream>>>(enc, WebfB, sW, Wv, attpart);
    softmax_kernel<<<32, 256, 0, stream>>>(attpart, out);
    ctx_partial<<<512, 256, 0, stream>>>(enc, out + 32768, part);
    ctx_reduce<<<128, 256, 0, stream>>>(part, out);
}